// Round 3
// baseline (2944.669 us; speedup 1.0000x reference)
//
#include <hip/hip_runtime.h>
#include <math.h>

#define Bsz  8192
#define Mdim 512
#define Ndim 2048
#define Kit  16
#define Pk   50
#define EPSv 0.01f

typedef __attribute__((ext_vector_type(8))) short bf16x8;
typedef __attribute__((ext_vector_type(4))) float f32x4;

// ---- bf16 split helpers: x = h + l ----------------------------------------
static __device__ __forceinline__ unsigned short f2bf(float f) {
    unsigned u = __float_as_uint(f);
    return (unsigned short)((u + 0x7fffu + ((u >> 16) & 1u)) >> 16);  // RNE
}
static __device__ __forceinline__ float bf2f(unsigned short h) {
    return __uint_as_float(((unsigned)h) << 16);
}

// ---- async global->LDS, 16B per lane (LDS dest = wave-uniform base) -------
static __device__ __forceinline__ void gl16(const void* g, void* l) {
    __builtin_amdgcn_global_load_lds(
        (const __attribute__((address_space(1))) unsigned int*)g,
        (__attribute__((address_space(3))) unsigned int*)l, 16, 0, 0);
}

// ---------------------------------------------------------------------------
// One-time: split A into bf16 planes Ah/Al [m][n] and AhT/AlT [n][m].
// ---------------------------------------------------------------------------
__global__ __launch_bounds__(256) void presplit_A(
    const float* __restrict__ A, unsigned short* __restrict__ Ah,
    unsigned short* __restrict__ Al, unsigned short* __restrict__ AhT,
    unsigned short* __restrict__ AlT)
{
    int idx = blockIdx.x * 256 + threadIdx.x;      // 0 .. M*N-1
    int m = idx >> 11, n = idx & (Ndim - 1);
    float a = A[idx];
    unsigned short h = f2bf(a);
    unsigned short l = f2bf(a - bf2f(h));
    Ah[idx] = h; Al[idx] = l;
    AhT[(size_t)n * Mdim + m] = h;
    AlT[(size_t)n * Mdim + m] = l;
}

// ---------------------------------------------------------------------------
// it=0: b = -y, stored as h/l planes. b row layout: [h 512][l 512] shorts.
// ---------------------------------------------------------------------------
__global__ __launch_bounds__(256) void split_negy_kernel(const float* __restrict__ y,
                                                         unsigned short* __restrict__ bS) {
    int i = blockIdx.x * 256 + threadIdx.x;        // float4 index
    float4 v = ((const float4*)y)[i];
    int idx = i * 4;
    int r = idx >> 9, c = idx & 511;
    float f0 = -v.x, f1 = -v.y, f2 = -v.z, f3 = -v.w;
    unsigned short h0 = f2bf(f0), h1 = f2bf(f1), h2 = f2bf(f2), h3 = f2bf(f3);
    ushort4 hv = make_ushort4(h0, h1, h2, h3);
    ushort4 lv = make_ushort4(f2bf(f0 - bf2f(h0)), f2bf(f1 - bf2f(h1)),
                              f2bf(f2 - bf2f(h2)), f2bf(f3 - bf2f(h3)));
    *(ushort4*)(bS + (size_t)r * 1024 + c)       = hv;
    *(ushort4*)(bS + (size_t)r * 1024 + 512 + c) = lv;
}

// ===========================================================================
// Both GEMMs: 128x128 tile, BK=32, 256 thr (4 waves, wave tile 64x64),
// 4-plane LDS (zh/zl/ah/al 8KB each = 32KB/tile), NBUF=4 -> 128KB, 1 blk/CU.
// Counted-vmcnt depth-3 pipeline:
//   phase t: STAGE(t+3) ; s_waitcnt vmcnt(24) ; s_barrier ; COMPUTE(t) ; s_barrier
// Tail phases wait 16/8/0.  No __syncthreads in the loop (no vmcnt(0) drain).
// Swizzle (proven in r2, 0 conflicts): 64B rows, slot ^= ((row>>1)&3)<<4 on
// stage-source AND ds_read.
// ===========================================================================

#define PIPE_BARRIER() __builtin_amdgcn_s_barrier()

// ---------------------------------------------------------------------------
// GEMM1 (NT): b[r][m] = sum_n z[r][n]*A[m][n] - y[r][m].
// z planes: zS row r = shorts [r*4096..): [zh 2048][zl 2048]. K=2048, NT=64.
// ---------------------------------------------------------------------------
__global__ __launch_bounds__(256, 1) void gemm1_mfma(
    const unsigned short* __restrict__ zS,
    const unsigned short* __restrict__ Ah, const unsigned short* __restrict__ Al,
    const float* __restrict__ y, unsigned short* __restrict__ bS)
{
    enum { NT = 64 };
    const int tid  = threadIdx.x;
    const int lane = tid & 63, w = tid >> 6;
    const int lm   = lane & 15, quad = lane >> 4;
    const int wr   = (w & 1) * 64, wn = (w >> 1) * 64;

    // bijective XCD swizzle (nwg=256, %8==0)
    int d   = blockIdx.y * gridDim.x + blockIdx.x;
    int sid = (d & 7) * 32 + (d >> 3);
    const int m0 = (sid & 3) * 128, r0 = (sid >> 2) * 128;

    // 4 bufs x (zh,zl,ah,al planes of 8KB) = 128KB
    __shared__ __attribute__((aligned(16))) unsigned short smem[4 * 16384];

    f32x4 acc[4][4];
#pragma unroll
    for (int i = 0; i < 4; i++)
#pragma unroll
        for (int j = 0; j < 4; j++) acc[i][j] = (f32x4)0.f;

    // staging: each 8KB plane = 8 chunks of 1KB; 2 chunks/wave/plane.
    const unsigned short *zhp[2], *zlp[2], *ahp[2], *alp[2]; int doff[2];
#pragma unroll
    for (int s = 0; s < 2; s++) {
        int off = ((w * 2 + s) << 10) + lane * 16;            // byte in plane
        int row = off >> 6;                                   // 0..127
        int kb  = (off & 63) ^ (((row >> 1) & 3) << 4);       // swizzled slot
        doff[s] = (w * 2 + s) << 10;                          // wave-uniform dest
        zhp[s]  = zS + (size_t)(r0 + row) * 4096 + (kb >> 1);
        zlp[s]  = zS + (size_t)(r0 + row) * 4096 + 2048 + (kb >> 1);
        ahp[s]  = Ah + (size_t)(m0 + row) * 2048 + (kb >> 1);
        alp[s]  = Al + (size_t)(m0 + row) * 2048 + (kb >> 1);
    }

    const int X = ((lm >> 1) & 3) << 4;

    auto STAGE = [&](int t) {
        char* base = (char*)smem + (t & 3) * 32768;
        const int ko = t * 32;
#pragma unroll
        for (int s = 0; s < 2; s++) {
            gl16(zhp[s] + ko, base +     0 + doff[s]);
            gl16(zlp[s] + ko, base +  8192 + doff[s]);
            gl16(ahp[s] + ko, base + 16384 + doff[s]);
            gl16(alp[s] + ko, base + 24576 + doff[s]);
        }
    };

    auto COMPUTE = [&](int bi) {
        const char* B0  = (const char*)smem + bi * 32768;
        const char* zhB = B0, *zlB = B0 + 8192, *ahB = B0 + 16384, *alB = B0 + 24576;
        const int cbx = (quad * 16) ^ X;
        bf16x8 ahf[4], alf[4];
#pragma unroll
        for (int fj = 0; fj < 4; fj++) {
            int ar = wn + fj * 16 + lm;
            ahf[fj] = *(const bf16x8*)(ahB + ar * 64 + cbx);
            alf[fj] = *(const bf16x8*)(alB + ar * 64 + cbx);
        }
#pragma unroll
        for (int fi = 0; fi < 4; fi++) {
            int zr = wr + fi * 16 + lm;
            bf16x8 zh8 = *(const bf16x8*)(zhB + zr * 64 + cbx);
            bf16x8 zl8 = *(const bf16x8*)(zlB + zr * 64 + cbx);
#pragma unroll
            for (int fj = 0; fj < 4; fj++) {
                acc[fi][fj] = __builtin_amdgcn_mfma_f32_16x16x32_bf16(zh8, ahf[fj], acc[fi][fj], 0, 0, 0);
                acc[fi][fj] = __builtin_amdgcn_mfma_f32_16x16x32_bf16(zh8, alf[fj], acc[fi][fj], 0, 0, 0);
                acc[fi][fj] = __builtin_amdgcn_mfma_f32_16x16x32_bf16(zl8, ahf[fj], acc[fi][fj], 0, 0, 0);
            }
        }
    };

    // prologue: 3 tiles in flight
    STAGE(0); STAGE(1); STAGE(2);

    for (int t = 0; t < NT - 3; ++t) {
        STAGE(t + 3);
        asm volatile("s_waitcnt vmcnt(24)" ::: "memory");   // tile t landed
        PIPE_BARRIER();
        __builtin_amdgcn_sched_barrier(0);
        COMPUTE(t & 3);
        PIPE_BARRIER();                                     // all waves done with buf
    }
    asm volatile("s_waitcnt vmcnt(16)" ::: "memory");
    PIPE_BARRIER(); __builtin_amdgcn_sched_barrier(0);
    COMPUTE((NT - 3) & 3); PIPE_BARRIER();
    asm volatile("s_waitcnt vmcnt(8)" ::: "memory");
    PIPE_BARRIER(); __builtin_amdgcn_sched_barrier(0);
    COMPUTE((NT - 2) & 3); PIPE_BARRIER();
    asm volatile("s_waitcnt vmcnt(0)" ::: "memory");
    PIPE_BARRIER(); __builtin_amdgcn_sched_barrier(0);
    COMPUTE((NT - 1) & 3);

    // epilogue: subtract y, split to planes.  D: col=lane&15, row=quad*4+r
#pragma unroll
    for (int fi = 0; fi < 4; fi++)
#pragma unroll
        for (int fj = 0; fj < 4; fj++)
#pragma unroll
            for (int r = 0; r < 4; r++) {
                int row = r0 + wr + fi * 16 + quad * 4 + r;
                int col = m0 + wn + fj * 16 + lm;
                float bv = acc[fi][fj][r] - y[(size_t)row * Mdim + col];
                unsigned short h = f2bf(bv);
                bS[(size_t)row * 1024 + col]       = h;
                bS[(size_t)row * 1024 + 512 + col] = f2bf(bv - bf2f(h));
            }
}

// ---------------------------------------------------------------------------
// GEMM2 (NN): c[r][n] = sum_m b[r][m]*A[m][n], c fp32.  K=512, NT=16.
// ---------------------------------------------------------------------------
__global__ __launch_bounds__(256, 1) void gemm2_mfma(
    const unsigned short* __restrict__ bS,
    const unsigned short* __restrict__ AhT, const unsigned short* __restrict__ AlT,
    float* __restrict__ c)
{
    enum { NT = 16 };
    const int tid  = threadIdx.x;
    const int lane = tid & 63, w = tid >> 6;
    const int lm   = lane & 15, quad = lane >> 4;
    const int wr   = (w & 1) * 64, wn = (w >> 1) * 64;

    // bijective XCD swizzle (nwg=1024, %8==0)
    int d   = blockIdx.y * gridDim.x + blockIdx.x;
    int sid = (d & 7) * 128 + (d >> 3);
    const int n0 = (sid & 15) * 128, r0 = (sid >> 4) * 128;

    __shared__ __attribute__((aligned(16))) unsigned short smem[4 * 16384];

    f32x4 acc[4][4];
#pragma unroll
    for (int i = 0; i < 4; i++)
#pragma unroll
        for (int j = 0; j < 4; j++) acc[i][j] = (f32x4)0.f;

    const unsigned short *bhp[2], *blp[2], *ahp[2], *alp[2]; int doff[2];
#pragma unroll
    for (int s = 0; s < 2; s++) {
        int off = ((w * 2 + s) << 10) + lane * 16;
        int row = off >> 6;                                   // 0..127
        int kb  = (off & 63) ^ (((row >> 1) & 3) << 4);
        doff[s] = (w * 2 + s) << 10;
        bhp[s]  = bS  + (size_t)(r0 + row) * 1024 + (kb >> 1);
        blp[s]  = bS  + (size_t)(r0 + row) * 1024 + 512 + (kb >> 1);
        ahp[s]  = AhT + (size_t)(n0 + row) * 512 + (kb >> 1);
        alp[s]  = AlT + (size_t)(n0 + row) * 512 + (kb >> 1);
    }

    const int X = ((lm >> 1) & 3) << 4;

    auto STAGE = [&](int t) {
        char* base = (char*)smem + (t & 3) * 32768;
        const int ko = t * 32;
#pragma unroll
        for (int s = 0; s < 2; s++) {
            gl16(bhp[s] + ko, base +     0 + doff[s]);
            gl16(blp[s] + ko, base +  8192 + doff[s]);
            gl16(ahp[s] + ko, base + 16384 + doff[s]);
            gl16(alp[s] + ko, base + 24576 + doff[s]);
        }
    };

    auto COMPUTE = [&](int bi) {
        const char* B0  = (const char*)smem + bi * 32768;
        const char* bhB = B0, *blB = B0 + 8192, *ahB = B0 + 16384, *alB = B0 + 24576;
        const int cbx = (quad * 16) ^ X;
        bf16x8 ahf[4], alf[4];
#pragma unroll
        for (int fj = 0; fj < 4; fj++) {
            int ar = wn + fj * 16 + lm;
            ahf[fj] = *(const bf16x8*)(ahB + ar * 64 + cbx);
            alf[fj] = *(const bf16x8*)(alB + ar * 64 + cbx);
        }
#pragma unroll
        for (int fi = 0; fi < 4; fi++) {
            int br = wr + fi * 16 + lm;
            bf16x8 bh8 = *(const bf16x8*)(bhB + br * 64 + cbx);
            bf16x8 bl8 = *(const bf16x8*)(blB + br * 64 + cbx);
#pragma unroll
            for (int fj = 0; fj < 4; fj++) {
                acc[fi][fj] = __builtin_amdgcn_mfma_f32_16x16x32_bf16(bh8, ahf[fj], acc[fi][fj], 0, 0, 0);
                acc[fi][fj] = __builtin_amdgcn_mfma_f32_16x16x32_bf16(bh8, alf[fj], acc[fi][fj], 0, 0, 0);
                acc[fi][fj] = __builtin_amdgcn_mfma_f32_16x16x32_bf16(bl8, ahf[fj], acc[fi][fj], 0, 0, 0);
            }
        }
    };

    STAGE(0); STAGE(1); STAGE(2);

    for (int t = 0; t < NT - 3; ++t) {
        STAGE(t + 3);
        asm volatile("s_waitcnt vmcnt(24)" ::: "memory");
        PIPE_BARRIER();
        __builtin_amdgcn_sched_barrier(0);
        COMPUTE(t & 3);
        PIPE_BARRIER();
    }
    asm volatile("s_waitcnt vmcnt(16)" ::: "memory");
    PIPE_BARRIER(); __builtin_amdgcn_sched_barrier(0);
    COMPUTE((NT - 3) & 3); PIPE_BARRIER();
    asm volatile("s_waitcnt vmcnt(8)" ::: "memory");
    PIPE_BARRIER(); __builtin_amdgcn_sched_barrier(0);
    COMPUTE((NT - 2) & 3); PIPE_BARRIER();
    asm volatile("s_waitcnt vmcnt(0)" ::: "memory");
    PIPE_BARRIER(); __builtin_amdgcn_sched_barrier(0);
    COMPUTE((NT - 1) & 3);

#pragma unroll
    for (int fi = 0; fi < 4; fi++)
#pragma unroll
        for (int fj = 0; fj < 4; fj++)
#pragma unroll
            for (int r = 0; r < 4; r++) {
                int row = r0 + wr + fi * 16 + quad * 4 + r;
                int col = n0 + wn + fj * 16 + lm;
                c[(size_t)row * Ndim + col] = acc[fi][fj][r];
            }
}

// ---------------------------------------------------------------------------
// Fused per-row: u = x - gamma*c; exact 50th-largest |u| (radix select);
// soft-threshold + overshoot; write x; write z as h/l planes in place of c.
// ---------------------------------------------------------------------------
__global__ __launch_bounds__(256) void topk_update_kernel(
    float* __restrict__ uz, float* __restrict__ x,
    const float* __restrict__ gamma, const float* __restrict__ theta,
    const float* __restrict__ a_param, const float* __restrict__ vv,
    const float* __restrict__ vu, int it)
{
    const int row = blockIdx.x;
    const int t   = threadIdx.x;
    float* crow = uz + (size_t)row * Ndim;
    float* xrow = x  + (size_t)row * Ndim;
    const float g = gamma[it];

    float4 c0 = *(const float4*)(crow + 4 * t);
    float4 c1 = *(const float4*)(crow + 4 * t + 1024);
    float4 x0 = *(const float4*)(xrow + 4 * t);
    float4 x1 = *(const float4*)(xrow + 4 * t + 1024);
    float cv[8] = { c0.x, c0.y, c0.z, c0.w, c1.x, c1.y, c1.z, c1.w };
    float xv[8] = { x0.x, x0.y, x0.z, x0.w, x1.x, x1.y, x1.z, x1.w };

    float uvals[8];
    unsigned keys[8];
#pragma unroll
    for (int e = 0; e < 8; e++) {
        uvals[e] = xv[e] - g * cv[e];
        keys[e]  = __float_as_uint(fabsf(uvals[e]));
    }

    __shared__ unsigned bins[256];
    __shared__ unsigned sel[2];

    unsigned prefix = 0;
    unsigned k = Pk;
#pragma unroll
    for (int pass = 0; pass < 4; ++pass) {
        const int shift = 24 - pass * 8;
        bins[t] = 0;
        __syncthreads();
        const unsigned himask = (pass == 0) ? 0u : (0xFFFFFFFFu << (shift + 8));
#pragma unroll
        for (int e = 0; e < 8; e++) {
            if ((keys[e] & himask) == prefix)
                atomicAdd(&bins[(keys[e] >> shift) & 255], 1u);
        }
        __syncthreads();
        if (t < 64) {
            const int i0 = 255 - 4 * t;
            unsigned c0b = bins[i0], c1b = bins[i0 - 1];
            unsigned c2b = bins[i0 - 2], c3b = bins[i0 - 3];
            unsigned s = c0b + c1b + c2b + c3b;
            unsigned sc = s;
#pragma unroll
            for (int off = 1; off < 64; off <<= 1) {
                unsigned o = __shfl_up(sc, (unsigned)off);
                if (t >= off) sc += o;
            }
            unsigned pre = sc - s;
            unsigned cs[4] = { c0b, c1b, c2b, c3b };
#pragma unroll
            for (int j = 0; j < 4; j++) {
                unsigned cb = cs[j];
                if (pre < k && pre + cb >= k) { sel[0] = (unsigned)(i0 - j); sel[1] = k - pre; }
                pre += cb;
            }
        }
        __syncthreads();
        prefix |= sel[0] << shift;
        k = sel[1];
    }
    const float thresh = __uint_as_float(prefix);

    const float th = theta[it];
    const float ap = a_param[it];
    const bool haveNext = (it + 1) < Kit;
    float tn = 0.f, vn = 0.f, vun = 0.f;
    if (haveNext) { tn = theta[it + 1]; vn = vv[it + 1]; vun = vu[it + 1]; }

    float xo[8];
    unsigned short zh8[8], zl8[8];
#pragma unroll
    for (int e = 0; e < 8; e++) {
        float uval = uvals[e];
        float au   = fabsf(uval);
        bool keep  = au > thresh;
        float shr  = copysignf(fmaxf(au - th, 0.f), uval);
        float xn   = keep ? uval : shr;
        float dlt  = xn - xv[e];
        float ov   = 1.f + ap / (fabsf(dlt) + EPSv);
        float xr   = xv[e] + ov * dlt;
        xo[e] = xr;
        float z = (1.f + tn * vun * __expf(-vn * fabsf(xr))) * xr;
        unsigned short h = f2bf(z);
        zh8[e] = h;
        zl8[e] = f2bf(z - bf2f(h));
    }
    float4 a0 = { xo[0], xo[1], xo[2], xo[3] };
    float4 a1 = { xo[4], xo[5], xo[6], xo[7] };
    *(float4*)(xrow + 4 * t) = a0;
    *(float4*)(xrow + 4 * t + 1024) = a1;
    if (haveNext) {
        unsigned short* zp = (unsigned short*)crow;   // row block: [zh 2048][zl 2048]
        *(ushort4*)(zp + 4 * t)        = make_ushort4(zh8[0], zh8[1], zh8[2], zh8[3]);
        *(ushort4*)(zp + 1024 + 4 * t) = make_ushort4(zh8[4], zh8[5], zh8[6], zh8[7]);
        *(ushort4*)(zp + 2048 + 4 * t) = make_ushort4(zl8[0], zl8[1], zl8[2], zl8[3]);
        *(ushort4*)(zp + 3072 + 4 * t) = make_ushort4(zl8[4], zl8[5], zl8[6], zl8[7]);
    }
}

// ---------------------------------------------------------------------------
extern "C" void kernel_launch(void* const* d_in, const int* in_sizes, int n_in,
                              void* d_out, int out_size, void* d_ws, size_t ws_size,
                              hipStream_t stream) {
    const float* y       = (const float*)d_in[0];   // (B,M)
    const float* A       = (const float*)d_in[1];   // (M,N)
    const float* gamma   = (const float*)d_in[2];
    const float* theta   = (const float*)d_in[3];
    const float* a_param = (const float*)d_in[4];
    const float* v       = (const float*)d_in[5];
    const float* vu      = (const float*)d_in[6];
    // d_in[7] theta_init (unused: multiplies x==0), d_in[8] info (unused)

    float* x = (float*)d_out;                       // (B,N) + 2K zeros

    // workspace layout (88 MB total)
    char* ws = (char*)d_ws;
    float*          uz = (float*)ws;                                  // 64 MB: c fp32 / z planes
    unsigned short* bS = (unsigned short*)(ws + (size_t)Bsz * Ndim * 4); // 16 MB: b planes
    unsigned short* Ah = (unsigned short*)(ws + (size_t)80 * 1024 * 1024);
    unsigned short* Al  = Ah  + (size_t)Mdim * Ndim;                  // 2 MB each
    unsigned short* AhT = Al  + (size_t)Mdim * Ndim;
    unsigned short* AlT = AhT + (size_t)Mdim * Ndim;

    hipMemsetAsync(d_out, 0, (size_t)out_size * sizeof(float), stream);

    dim3 blk(256);
    dim3 g1(Mdim / 128, Bsz / 128);     // 4 x 64  = 256 blocks (1/CU)
    dim3 g2(Ndim / 128, Bsz / 128);     // 16 x 64 = 1024 blocks

    presplit_A<<<(Mdim * Ndim) / 256, blk, 0, stream>>>(A, Ah, Al, AhT, AlT);
    split_negy_kernel<<<(Bsz * Mdim / 4) / 256, blk, 0, stream>>>(y, bS);

    for (int it = 0; it < Kit; ++it) {
        if (it > 0)
            gemm1_mfma<<<g1, blk, 0, stream>>>((const unsigned short*)uz, Ah, Al, y, bS);
        gemm2_mfma<<<g2, blk, 0, stream>>>(bS, AhT, AlT, uz);
        topk_update_kernel<<<Bsz, blk, 0, stream>>>(uz, x, gamma, theta, a_param, v, vu, it);
    }
}

// Round 4
// 2566.390 us; speedup vs baseline: 1.1474x; 1.1474x over previous
//
#include <hip/hip_runtime.h>
#include <math.h>

#define Bsz  8192
#define Mdim 512
#define Ndim 2048
#define Kit  16
#define Pk   50
#define EPSv 0.01f

typedef __attribute__((ext_vector_type(8))) short bf16x8;
typedef __attribute__((ext_vector_type(4))) float f32x4;

// ---- bf16 split helpers: x = h + l ----------------------------------------
static __device__ __forceinline__ unsigned short f2bf(float f) {
    unsigned u = __float_as_uint(f);
    return (unsigned short)((u + 0x7fffu + ((u >> 16) & 1u)) >> 16);  // RNE
}
static __device__ __forceinline__ float bf2f(unsigned short h) {
    return __uint_as_float(((unsigned)h) << 16);
}

// ---- async global->LDS, 16B per lane (LDS dest = wave-uniform base) -------
static __device__ __forceinline__ void gl16(const void* g, void* l) {
    __builtin_amdgcn_global_load_lds(
        (const __attribute__((address_space(1))) unsigned int*)g,
        (__attribute__((address_space(3))) unsigned int*)l, 16, 0, 0);
}

#define PIPE_BARRIER() __builtin_amdgcn_s_barrier()

#define MFMA3(acc_, bh_, bl_, ah_, al_)                                         \
    acc_ = __builtin_amdgcn_mfma_f32_16x16x32_bf16(bh_, ah_, acc_, 0, 0, 0);    \
    acc_ = __builtin_amdgcn_mfma_f32_16x16x32_bf16(bh_, al_, acc_, 0, 0, 0);    \
    acc_ = __builtin_amdgcn_mfma_f32_16x16x32_bf16(bl_, ah_, acc_, 0, 0, 0);

// ---------------------------------------------------------------------------
// One-time: split A into bf16 planes Ah/Al [m][n] and AhT/AlT [n][m].
// ---------------------------------------------------------------------------
__global__ __launch_bounds__(256) void presplit_A(
    const float* __restrict__ A, unsigned short* __restrict__ Ah,
    unsigned short* __restrict__ Al, unsigned short* __restrict__ AhT,
    unsigned short* __restrict__ AlT)
{
    int idx = blockIdx.x * 256 + threadIdx.x;      // 0 .. M*N-1
    int m = idx >> 11, n = idx & (Ndim - 1);
    float a = A[idx];
    unsigned short h = f2bf(a);
    unsigned short l = f2bf(a - bf2f(h));
    Ah[idx] = h; Al[idx] = l;
    AhT[(size_t)n * Mdim + m] = h;
    AlT[(size_t)n * Mdim + m] = l;
}

// ---------------------------------------------------------------------------
// it=0: b = -y, stored as h/l planes. b row layout: [h 512][l 512] shorts.
// ---------------------------------------------------------------------------
__global__ __launch_bounds__(256) void split_negy_kernel(const float* __restrict__ y,
                                                         unsigned short* __restrict__ bS) {
    int i = blockIdx.x * 256 + threadIdx.x;        // float4 index
    float4 v = ((const float4*)y)[i];
    int idx = i * 4;
    int r = idx >> 9, c = idx & 511;
    float f0 = -v.x, f1 = -v.y, f2 = -v.z, f3 = -v.w;
    unsigned short h0 = f2bf(f0), h1 = f2bf(f1), h2 = f2bf(f2), h3 = f2bf(f3);
    ushort4 hv = make_ushort4(h0, h1, h2, h3);
    ushort4 lv = make_ushort4(f2bf(f0 - bf2f(h0)), f2bf(f1 - bf2f(h1)),
                              f2bf(f2 - bf2f(h2)), f2bf(f3 - bf2f(h3)));
    *(ushort4*)(bS + (size_t)r * 1024 + c)       = hv;
    *(ushort4*)(bS + (size_t)r * 1024 + 512 + c) = lv;
}

// ---------------------------------------------------------------------------
// GEMM1 (NT): b[r][m] = sum_n z[r][n]*A[m][n] - y[r][m].
// Round-1 structure (best measured ~63us): tile 128(r)x64(m), BK=64,
// single-buffer 48KB (3 blk/CU), 2-barrier loop, 128B-row swizzle.
// ---------------------------------------------------------------------------
__global__ __launch_bounds__(256) void gemm1_mfma(
    const unsigned short* __restrict__ zS,
    const unsigned short* __restrict__ Ah, const unsigned short* __restrict__ Al,
    const float* __restrict__ y, unsigned short* __restrict__ bS)
{
    const int tid  = threadIdx.x;
    const int lane = tid & 63, w = tid >> 6;
    const int lm   = lane & 15, quad = lane >> 4;
    const int wr   = (w & 1) * 64, wm = (w >> 1) * 32;

    // bijective XCD swizzle (nwg=512, %8==0)
    int d   = blockIdx.y * gridDim.x + blockIdx.x;
    int sid = (d & 7) * 64 + (d >> 3);
    const int m0 = (sid & 7) * 64, r0 = (sid >> 3) * 128;

    __shared__ __attribute__((aligned(16))) unsigned short zh_s[128 * 64];
    __shared__ __attribute__((aligned(16))) unsigned short zl_s[128 * 64];
    __shared__ __attribute__((aligned(16))) unsigned short ah_s[64 * 64];
    __shared__ __attribute__((aligned(16))) unsigned short al_s[64 * 64];

    f32x4 acc[4][2];
#pragma unroll
    for (int i = 0; i < 4; i++)
#pragma unroll
        for (int j = 0; j < 2; j++) acc[i][j] = (f32x4)0.f;

    // z staging: plane 16KB = 16 chunks of 1KB; 4/wave.
    const unsigned short* zsh[4]; const unsigned short* zsl[4]; int zoff[4];
#pragma unroll
    for (int s = 0; s < 4; s++) {
        int off = ((w * 4 + s) << 10) + lane * 16;
        int row = off >> 7;
        int kb  = (off & 127) ^ ((row & 7) << 4);
        zoff[s] = (w * 4 + s) << 10;
        zsh[s]  = zS + (size_t)(r0 + row) * 4096 + (kb >> 1);
        zsl[s]  = zS + (size_t)(r0 + row) * 4096 + 2048 + (kb >> 1);
    }
    // A staging: plane 8KB = 8 chunks; 2/wave.
    const unsigned short* ash[2]; const unsigned short* asl[2]; int aoff[2];
#pragma unroll
    for (int s = 0; s < 2; s++) {
        int off = ((w * 2 + s) << 10) + lane * 16;
        int row = off >> 7;
        int kb  = (off & 127) ^ ((row & 7) << 4);
        aoff[s] = (w * 2 + s) << 10;
        ash[s]  = Ah + (size_t)(m0 + row) * 2048 + (kb >> 1);
        asl[s]  = Al + (size_t)(m0 + row) * 2048 + (kb >> 1);
    }

    const int X = (lm & 7) << 4;   // all fragment rows have row&7 == lm&7

    for (int k0 = 0; k0 < Ndim; k0 += 64) {
        __syncthreads();
#pragma unroll
        for (int s = 0; s < 4; s++) {
            gl16(zsh[s], (char*)zh_s + zoff[s]);
            gl16(zsl[s], (char*)zl_s + zoff[s]);
            zsh[s] += 64; zsl[s] += 64;
        }
#pragma unroll
        for (int s = 0; s < 2; s++) {
            gl16(ash[s], (char*)ah_s + aoff[s]);
            gl16(asl[s], (char*)al_s + aoff[s]);
            ash[s] += 64; asl[s] += 64;
        }
        __syncthreads();   // drains vmcnt(0) -> tile ready
#pragma unroll
        for (int kk = 0; kk < 2; kk++) {
            const int cbx = (kk * 64 + quad * 16) ^ X;
            bf16x8 bhf[2], blf[2];
#pragma unroll
            for (int fj = 0; fj < 2; fj++) {
                int ar = wm + fj * 16 + lm;
                bhf[fj] = *(const bf16x8*)((const char*)ah_s + ar * 128 + cbx);
                blf[fj] = *(const bf16x8*)((const char*)al_s + ar * 128 + cbx);
            }
#pragma unroll
            for (int fi = 0; fi < 4; fi++) {
                int zr = wr + fi * 16 + lm;
                bf16x8 zh8 = *(const bf16x8*)((const char*)zh_s + zr * 128 + cbx);
                bf16x8 zl8 = *(const bf16x8*)((const char*)zl_s + zr * 128 + cbx);
#pragma unroll
                for (int fj = 0; fj < 2; fj++) {
                    MFMA3(acc[fi][fj], zh8, zl8, bhf[fj], blf[fj]);
                }
            }
        }
    }
    // epilogue: subtract y, split to planes.  D: col=lane&15, row=quad*4+r
#pragma unroll
    for (int fi = 0; fi < 4; fi++)
#pragma unroll
        for (int fj = 0; fj < 2; fj++)
#pragma unroll
            for (int r = 0; r < 4; r++) {
                int row = r0 + wr + fi * 16 + quad * 4 + r;
                int col = m0 + wm + fj * 16 + lm;
                float bv = acc[fi][fj][r] - y[(size_t)row * Mdim + col];
                unsigned short h = f2bf(bv);
                bS[(size_t)row * 1024 + col]       = h;
                bS[(size_t)row * 1024 + 512 + col] = f2bf(bv - bf2f(h));
            }
}

// ---------------------------------------------------------------------------
// GEMM2 (NN): c[r][n] = sum_m b[r][m]*A[m][n], c fp32.
// 8-phase-style m201 port: tile 256x256, BK=32, 512 thr (8 waves 2Mx4N,
// wave tile 128x64), dbuf 2x64KB = 128KB (1 blk/CU, 2 waves/SIMD).
// Per K-step: 2 fine phases, each {ds_read subtile (+stage in P0) ->
// s_barrier -> lgkmcnt(0) -> sched_barrier -> setprio(1) -> 48 MFMA ->
// setprio(0) -> barrier}; vmcnt(0) once per K-step with ~2-phase lead.
// Swizzle: 64B rows, slot ^= ((row>>1)&3)<<4 on stage-source AND ds_read.
// ---------------------------------------------------------------------------
__global__ __launch_bounds__(512, 2) void gemm2_mfma(
    const unsigned short* __restrict__ bS,
    const unsigned short* __restrict__ AhT, const unsigned short* __restrict__ AlT,
    float* __restrict__ c)
{
    enum { NT = 16 };                              // K = 512 / BK=32
    const int tid  = threadIdx.x;
    const int lane = tid & 63, w = tid >> 6;       // 8 waves
    const int lm   = lane & 15, quad = lane >> 4;
    const int wrow = (w >> 2) * 128;               // 2 row-waves
    const int wcol = (w & 3) * 64;                 // 4 col-waves

    // bijective XCD swizzle (nwg=256, %8==0)
    int d   = blockIdx.y * gridDim.x + blockIdx.x;
    int sid = (d & 7) * 32 + (d >> 3);
    const int n0 = (sid & 7) * 256, r0 = (sid >> 3) * 256;

    // 2 bufs x 64KB; per buf: bh 16K | bl 16K | ah 16K | al 16K (bytes)
    __shared__ __attribute__((aligned(16))) unsigned short smem[2 * 32768];

    f32x4 acc[8][4];
#pragma unroll
    for (int i = 0; i < 8; i++)
#pragma unroll
        for (int j = 0; j < 4; j++) acc[i][j] = (f32x4)0.f;

    // staging: each 16KB plane = 16 chunks of 1KB; 2 chunks/wave/plane.
    const unsigned short *bhp[2], *blp[2], *ahp[2], *alp[2]; int doff[2];
#pragma unroll
    for (int s = 0; s < 2; s++) {
        int off = ((w * 2 + s) << 10) + lane * 16;            // byte in plane
        int row = off >> 6;                                   // 0..255
        int kb  = (off & 63) ^ (((row >> 1) & 3) << 4);       // swizzled slot
        doff[s] = (w * 2 + s) << 10;
        bhp[s]  = bS  + (size_t)(r0 + row) * 1024 + (kb >> 1);
        blp[s]  = bS  + (size_t)(r0 + row) * 1024 + 512 + (kb >> 1);
        ahp[s]  = AhT + (size_t)(n0 + row) * 512 + (kb >> 1);
        alp[s]  = AlT + (size_t)(n0 + row) * 512 + (kb >> 1);
    }

    const int X   = ((lm >> 1) & 3) << 4;
    const int cbx = (quad * 16) ^ X;

    auto STAGE = [&](int t) {
        char* base = (char*)smem + (t & 1) * 65536;
        const int ko = t * 32;
#pragma unroll
        for (int s = 0; s < 2; s++) {
            gl16(bhp[s] + ko, base +     0 + doff[s]);
            gl16(blp[s] + ko, base + 16384 + doff[s]);
            gl16(ahp[s] + ko, base + 32768 + doff[s]);
            gl16(alp[s] + ko, base + 49152 + doff[s]);
        }
    };

    // prologue: tile 0 -> buf0
    STAGE(0);
    asm volatile("s_waitcnt vmcnt(0)" ::: "memory");
    PIPE_BARRIER();

#pragma unroll 2
    for (int t = 0; t < NT; ++t) {
        const char* B0  = (const char*)smem + (t & 1) * 65536;
        const char* bhB = B0, *blB = B0 + 16384;
        const char* ahB = B0 + 32768, *alB = B0 + 49152;

        // ---- P0: read B-side (all 4 col-frags) + row-frags 0..3; stage next
        bf16x8 ahf[4], alf[4], bhf[4], blf[4];
#pragma unroll
        for (int fj = 0; fj < 4; fj++) {
            int ar = wcol + fj * 16 + lm;
            ahf[fj] = *(const bf16x8*)(ahB + ar * 64 + cbx);
            alf[fj] = *(const bf16x8*)(alB + ar * 64 + cbx);
        }
#pragma unroll
        for (int fi = 0; fi < 4; fi++) {
            int br = wrow + fi * 16 + lm;
            bhf[fi] = *(const bf16x8*)(bhB + br * 64 + cbx);
            blf[fi] = *(const bf16x8*)(blB + br * 64 + cbx);
        }
        if (t + 1 < NT) STAGE(t + 1);
        PIPE_BARRIER();
        asm volatile("s_waitcnt lgkmcnt(0)" ::: "memory");
        __builtin_amdgcn_sched_barrier(0);
        __builtin_amdgcn_s_setprio(1);
#pragma unroll
        for (int fi = 0; fi < 4; fi++)
#pragma unroll
            for (int fj = 0; fj < 4; fj++) {
                MFMA3(acc[fi][fj], bhf[fi], blf[fi], ahf[fj], alf[fj]);
            }
        __builtin_amdgcn_s_setprio(0);
        PIPE_BARRIER();

        // ---- P1: row-frags 4..7
#pragma unroll
        for (int fi = 0; fi < 4; fi++) {
            int br = wrow + (fi + 4) * 16 + lm;
            bhf[fi] = *(const bf16x8*)(bhB + br * 64 + cbx);
            blf[fi] = *(const bf16x8*)(blB + br * 64 + cbx);
        }
        PIPE_BARRIER();
        asm volatile("s_waitcnt lgkmcnt(0)" ::: "memory");
        __builtin_amdgcn_sched_barrier(0);
        __builtin_amdgcn_s_setprio(1);
#pragma unroll
        for (int fi = 0; fi < 4; fi++)
#pragma unroll
            for (int fj = 0; fj < 4; fj++) {
                MFMA3(acc[fi + 4][fj], bhf[fi], blf[fi], ahf[fj], alf[fj]);
            }
        __builtin_amdgcn_s_setprio(0);
        // next tile's loads were issued a full phase+ ago -> near-free wait
        asm volatile("s_waitcnt vmcnt(0)" ::: "memory");
        PIPE_BARRIER();
    }

    // epilogue: D col=lane&15, row=quad*4+r
#pragma unroll
    for (int fi = 0; fi < 8; fi++)
#pragma unroll
        for (int fj = 0; fj < 4; fj++)
#pragma unroll
            for (int r = 0; r < 4; r++) {
                int row = r0 + wrow + fi * 16 + quad * 4 + r;
                int col = n0 + wcol + fj * 16 + lm;
                c[(size_t)row * Ndim + col] = acc[fi][fj][r];
            }
}

// ---------------------------------------------------------------------------
// Fused per-row: u = x - gamma*c; exact 50th-largest |u| (radix select);
// soft-threshold + overshoot; write x; write z as h/l planes in place of c.
// ---------------------------------------------------------------------------
__global__ __launch_bounds__(256) void topk_update_kernel(
    float* __restrict__ uz, float* __restrict__ x,
    const float* __restrict__ gamma, const float* __restrict__ theta,
    const float* __restrict__ a_param, const float* __restrict__ vv,
    const float* __restrict__ vu, int it)
{
    const int row = blockIdx.x;
    const int t   = threadIdx.x;
    float* crow = uz + (size_t)row * Ndim;
    float* xrow = x  + (size_t)row * Ndim;
    const float g = gamma[it];

    float4 c0 = *(const float4*)(crow + 4 * t);
    float4 c1 = *(const float4*)(crow + 4 * t + 1024);
    float4 x0 = *(const float4*)(xrow + 4 * t);
    float4 x1 = *(const float4*)(xrow + 4 * t + 1024);
    float cv[8] = { c0.x, c0.y, c0.z, c0.w, c1.x, c1.y, c1.z, c1.w };
    float xv[8] = { x0.x, x0.y, x0.z, x0.w, x1.x, x1.y, x1.z, x1.w };

    float uvals[8];
    unsigned keys[8];
#pragma unroll
    for (int e = 0; e < 8; e++) {
        uvals[e] = xv[e] - g * cv[e];
        keys[e]  = __float_as_uint(fabsf(uvals[e]));
    }

    __shared__ unsigned bins[256];
    __shared__ unsigned sel[2];

    unsigned prefix = 0;
    unsigned k = Pk;
#pragma unroll
    for (int pass = 0; pass < 4; ++pass) {
        const int shift = 24 - pass * 8;
        bins[t] = 0;
        __syncthreads();
        const unsigned himask = (pass == 0) ? 0u : (0xFFFFFFFFu << (shift + 8));
#pragma unroll
        for (int e = 0; e < 8; e++) {
            if ((keys[e] & himask) == prefix)
                atomicAdd(&bins[(keys[e] >> shift) & 255], 1u);
        }
        __syncthreads();
        if (t < 64) {
            const int i0 = 255 - 4 * t;
            unsigned c0b = bins[i0], c1b = bins[i0 - 1];
            unsigned c2b = bins[i0 - 2], c3b = bins[i0 - 3];
            unsigned s = c0b + c1b + c2b + c3b;
            unsigned sc = s;
#pragma unroll
            for (int off = 1; off < 64; off <<= 1) {
                unsigned o = __shfl_up(sc, (unsigned)off);
                if (t >= off) sc += o;
            }
            unsigned pre = sc - s;
            unsigned cs[4] = { c0b, c1b, c2b, c3b };
#pragma unroll
            for (int j = 0; j < 4; j++) {
                unsigned cb = cs[j];
                if (pre < k && pre + cb >= k) { sel[0] = (unsigned)(i0 - j); sel[1] = k - pre; }
                pre += cb;
            }
        }
        __syncthreads();
        prefix |= sel[0] << shift;
        k = sel[1];
    }
    const float thresh = __uint_as_float(prefix);

    const float th = theta[it];
    const float ap = a_param[it];
    const bool haveNext = (it + 1) < Kit;
    float tn = 0.f, vn = 0.f, vun = 0.f;
    if (haveNext) { tn = theta[it + 1]; vn = vv[it + 1]; vun = vu[it + 1]; }

    float xo[8];
    unsigned short zh8[8], zl8[8];
#pragma unroll
    for (int e = 0; e < 8; e++) {
        float uval = uvals[e];
        float au   = fabsf(uval);
        bool keep  = au > thresh;
        float shr  = copysignf(fmaxf(au - th, 0.f), uval);
        float xn   = keep ? uval : shr;
        float dlt  = xn - xv[e];
        float ov   = 1.f + ap / (fabsf(dlt) + EPSv);
        float xr   = xv[e] + ov * dlt;
        xo[e] = xr;
        float z = (1.f + tn * vun * __expf(-vn * fabsf(xr))) * xr;
        unsigned short h = f2bf(z);
        zh8[e] = h;
        zl8[e] = f2bf(z - bf2f(h));
    }
    float4 a0 = { xo[0], xo[1], xo[2], xo[3] };
    float4 a1 = { xo[4], xo[5], xo[6], xo[7] };
    *(float4*)(xrow + 4 * t) = a0;
    *(float4*)(xrow + 4 * t + 1024) = a1;
    if (haveNext) {
        unsigned short* zp = (unsigned short*)crow;   // row block: [zh 2048][zl 2048]
        *(ushort4*)(zp + 4 * t)        = make_ushort4(zh8[0], zh8[1], zh8[2], zh8[3]);
        *(ushort4*)(zp + 1024 + 4 * t) = make_ushort4(zh8[4], zh8[5], zh8[6], zh8[7]);
        *(ushort4*)(zp + 2048 + 4 * t) = make_ushort4(zl8[0], zl8[1], zl8[2], zl8[3]);
        *(ushort4*)(zp + 3072 + 4 * t) = make_ushort4(zl8[4], zl8[5], zl8[6], zl8[7]);
    }
}

// ---------------------------------------------------------------------------
extern "C" void kernel_launch(void* const* d_in, const int* in_sizes, int n_in,
                              void* d_out, int out_size, void* d_ws, size_t ws_size,
                              hipStream_t stream) {
    const float* y       = (const float*)d_in[0];   // (B,M)
    const float* A       = (const float*)d_in[1];   // (M,N)
    const float* gamma   = (const float*)d_in[2];
    const float* theta   = (const float*)d_in[3];
    const float* a_param = (const float*)d_in[4];
    const float* v       = (const float*)d_in[5];
    const float* vu      = (const float*)d_in[6];
    // d_in[7] theta_init (unused: multiplies x==0), d_in[8] info (unused)

    float* x = (float*)d_out;                       // (B,N) + 2K zeros

    // workspace layout (88 MB total)
    char* ws = (char*)d_ws;
    float*          uz = (float*)ws;                                  // 64 MB: c fp32 / z planes
    unsigned short* bS = (unsigned short*)(ws + (size_t)Bsz * Ndim * 4); // 16 MB: b planes
    unsigned short* Ah = (unsigned short*)(ws + (size_t)80 * 1024 * 1024);
    unsigned short* Al  = Ah  + (size_t)Mdim * Ndim;                  // 2 MB each
    unsigned short* AhT = Al  + (size_t)Mdim * Ndim;
    unsigned short* AlT = AhT + (size_t)Mdim * Ndim;

    hipMemsetAsync(d_out, 0, (size_t)out_size * sizeof(float), stream);

    dim3 g1(Mdim / 64, Bsz / 128);      // 8 x 64  = 512 blocks
    dim3 g2(Ndim / 256, Bsz / 256);     // 8 x 32  = 256 blocks

    presplit_A<<<(Mdim * Ndim) / 256, dim3(256), 0, stream>>>(A, Ah, Al, AhT, AlT);
    split_negy_kernel<<<(Bsz * Mdim / 4) / 256, dim3(256), 0, stream>>>(y, bS);

    for (int it = 0; it < Kit; ++it) {
        if (it > 0)
            gemm1_mfma<<<g1, dim3(256), 0, stream>>>((const unsigned short*)uz, Ah, Al, y, bS);
        gemm2_mfma<<<g2, dim3(512), 0, stream>>>(bS, AhT, AlT, uz);
        topk_update_kernel<<<Bsz, dim3(256), 0, stream>>>(uz, x, gamma, theta, a_param, v, vu, it);
    }
}

// Round 5
// 2423.706 us; speedup vs baseline: 1.2149x; 1.0589x over previous
//
#include <hip/hip_runtime.h>
#include <math.h>

#define Bsz  8192
#define Mdim 512
#define Ndim 2048
#define Kit  16
#define Pk   50
#define EPSv 0.01f

typedef __attribute__((ext_vector_type(8))) short bf16x8;
typedef __attribute__((ext_vector_type(4))) float f32x4;

// ---- bf16 split helpers: x = h + l ----------------------------------------
static __device__ __forceinline__ unsigned short f2bf(float f) {
    unsigned u = __float_as_uint(f);
    return (unsigned short)((u + 0x7fffu + ((u >> 16) & 1u)) >> 16);  // RNE
}
static __device__ __forceinline__ float bf2f(unsigned short h) {
    return __uint_as_float(((unsigned)h) << 16);
}

// ---- async global->LDS, 16B per lane (LDS dest = wave-uniform base) -------
static __device__ __forceinline__ void gl16(const void* g, void* l) {
    __builtin_amdgcn_global_load_lds(
        (const __attribute__((address_space(1))) unsigned int*)g,
        (__attribute__((address_space(3))) unsigned int*)l, 16, 0, 0);
}

#define PIPE_BARRIER() __builtin_amdgcn_s_barrier()

#define MFMA3(acc_, bh_, bl_, ah_, al_)                                         \
    acc_ = __builtin_amdgcn_mfma_f32_16x16x32_bf16(bh_, ah_, acc_, 0, 0, 0);    \
    acc_ = __builtin_amdgcn_mfma_f32_16x16x32_bf16(bh_, al_, acc_, 0, 0, 0);    \
    acc_ = __builtin_amdgcn_mfma_f32_16x16x32_bf16(bl_, ah_, acc_, 0, 0, 0);

// ---------------------------------------------------------------------------
// One-time: split A into bf16 planes Ah/Al [m][n] and AhT/AlT [n][m].
// ---------------------------------------------------------------------------
__global__ __launch_bounds__(256) void presplit_A(
    const float* __restrict__ A, unsigned short* __restrict__ Ah,
    unsigned short* __restrict__ Al, unsigned short* __restrict__ AhT,
    unsigned short* __restrict__ AlT)
{
    int idx = blockIdx.x * 256 + threadIdx.x;      // 0 .. M*N-1
    int m = idx >> 11, n = idx & (Ndim - 1);
    float a = A[idx];
    unsigned short h = f2bf(a);
    unsigned short l = f2bf(a - bf2f(h));
    Ah[idx] = h; Al[idx] = l;
    AhT[(size_t)n * Mdim + m] = h;
    AlT[(size_t)n * Mdim + m] = l;
}

// ---------------------------------------------------------------------------
// it=0: b = -y, stored as h/l planes. b row layout: [h 512][l 512] shorts.
// ---------------------------------------------------------------------------
__global__ __launch_bounds__(256) void split_negy_kernel(const float* __restrict__ y,
                                                         unsigned short* __restrict__ bS) {
    int i = blockIdx.x * 256 + threadIdx.x;        // float4 index
    float4 v = ((const float4*)y)[i];
    int idx = i * 4;
    int r = idx >> 9, c = idx & 511;
    float f0 = -v.x, f1 = -v.y, f2 = -v.z, f3 = -v.w;
    unsigned short h0 = f2bf(f0), h1 = f2bf(f1), h2 = f2bf(f2), h3 = f2bf(f3);
    ushort4 hv = make_ushort4(h0, h1, h2, h3);
    ushort4 lv = make_ushort4(f2bf(f0 - bf2f(h0)), f2bf(f1 - bf2f(h1)),
                              f2bf(f2 - bf2f(h2)), f2bf(f3 - bf2f(h3)));
    *(ushort4*)(bS + (size_t)r * 1024 + c)       = hv;
    *(ushort4*)(bS + (size_t)r * 1024 + 512 + c) = lv;
}

// ---------------------------------------------------------------------------
// GEMM1 (NT): b[r][m] = sum_n z[r][n]*A[m][n] - y[r][m].
// K-split-in-block: 512 thr = 2 K-groups x 4 waves. Each group computes the
// full 128x128 tile over K/2=1024 (wave tile 64x64, fi=fj=4, read:MFMA=1:3),
// using the proven 2-phase counted-vmcnt pipeline. LDS: 2 bufs x 64KB
// ([g][zh|zl|ah|al] 8KB planes). Combine: group1 -> padded LDS fp32,
// group0 adds + subtracts y + splits to planes.
// Swizzle: 64B rows, slot ^= ((row>>1)&3)<<4 on stage-source AND ds_read.
// ---------------------------------------------------------------------------
__global__ __launch_bounds__(512, 2) void gemm1_mfma(
    const unsigned short* __restrict__ zS,
    const unsigned short* __restrict__ Ah, const unsigned short* __restrict__ Al,
    const float* __restrict__ y, unsigned short* __restrict__ bS)
{
    enum { NT = 32 };                              // per-group K-steps: 1024/32
    const int tid  = threadIdx.x;
    const int lane = tid & 63, w = tid >> 6;       // 8 waves
    const int lm   = lane & 15, quad = lane >> 4;
    const int g    = w >> 2;                       // K-group 0/1
    const int wg   = w & 3;
    const int wrow = (wg >> 1) * 64;               // 2r x 2c within group
    const int wcol = (wg & 1) * 64;

    // bijective XCD swizzle (nwg=256, %8==0)
    int d   = blockIdx.y * gridDim.x + blockIdx.x;
    int sid = (d & 7) * 32 + (d >> 3);
    const int m0 = (sid & 3) * 128, r0 = (sid >> 2) * 128;

    // 2 bufs x 64KB = 128KB; per buf: [g][plane zh|zl|ah|al][8KB]
    __shared__ __attribute__((aligned(16))) unsigned short smem[2 * 32768];

    f32x4 acc[4][4];
#pragma unroll
    for (int i = 0; i < 4; i++)
#pragma unroll
        for (int j = 0; j < 4; j++) acc[i][j] = (f32x4)0.f;

    // staging: each 8KB plane = 8 chunks of 1KB; group's 4 waves cover it
    // (2 chunks/wave/plane -> 8 gl16 per wave per K-step).
    const unsigned short *zhp[2], *zlp[2], *ahp[2], *alp[2]; int doff[2];
#pragma unroll
    for (int s = 0; s < 2; s++) {
        int off = ((wg * 2 + s) << 10) + lane * 16;           // byte in plane
        int row = off >> 6;                                   // 0..127
        int kb  = (off & 63) ^ (((row >> 1) & 3) << 4);       // swizzled slot
        doff[s] = (wg * 2 + s) << 10;
        int kbase = g * 1024 + (kb >> 1);                     // shorts
        zhp[s]  = zS + (size_t)(r0 + row) * 4096 + kbase;
        zlp[s]  = zS + (size_t)(r0 + row) * 4096 + 2048 + kbase;
        ahp[s]  = Ah + (size_t)(m0 + row) * 2048 + kbase;     // row = m index
        alp[s]  = Al + (size_t)(m0 + row) * 2048 + kbase;
    }

    const int X   = ((lm >> 1) & 3) << 4;
    const int cbx = (quad * 16) ^ X;

    auto STAGE = [&](int t) {
        char* base = (char*)smem + (t & 1) * 65536 + g * 32768;
        const int ko = t * 32;
#pragma unroll
        for (int s = 0; s < 2; s++) {
            gl16(zhp[s] + ko, base +     0 + doff[s]);
            gl16(zlp[s] + ko, base +  8192 + doff[s]);
            gl16(ahp[s] + ko, base + 16384 + doff[s]);
            gl16(alp[s] + ko, base + 24576 + doff[s]);
        }
    };

    // prologue: tile 0 -> buf0
    STAGE(0);
    asm volatile("s_waitcnt vmcnt(0)" ::: "memory");
    PIPE_BARRIER();

#pragma unroll 2
    for (int t = 0; t < NT; ++t) {
        const char* B0  = (const char*)smem + (t & 1) * 65536 + g * 32768;
        const char* zhB = B0, *zlB = B0 + 8192;
        const char* ahB = B0 + 16384, *alB = B0 + 24576;

        // ---- P0: a-side col frags (8 reads) + z row frags 0..1; stage next
        bf16x8 ahf[4], alf[4], zhf[2], zlf[2];
#pragma unroll
        for (int fj = 0; fj < 4; fj++) {
            int ar = wcol + fj * 16 + lm;
            ahf[fj] = *(const bf16x8*)(ahB + ar * 64 + cbx);
            alf[fj] = *(const bf16x8*)(alB + ar * 64 + cbx);
        }
#pragma unroll
        for (int fi = 0; fi < 2; fi++) {
            int zr = wrow + fi * 16 + lm;
            zhf[fi] = *(const bf16x8*)(zhB + zr * 64 + cbx);
            zlf[fi] = *(const bf16x8*)(zlB + zr * 64 + cbx);
        }
        if (t + 1 < NT) STAGE(t + 1);
        PIPE_BARRIER();
        asm volatile("s_waitcnt lgkmcnt(0)" ::: "memory");
        __builtin_amdgcn_sched_barrier(0);
        __builtin_amdgcn_s_setprio(1);
#pragma unroll
        for (int fi = 0; fi < 2; fi++)
#pragma unroll
            for (int fj = 0; fj < 4; fj++) {
                MFMA3(acc[fi][fj], zhf[fi], zlf[fi], ahf[fj], alf[fj]);
            }
        __builtin_amdgcn_s_setprio(0);
        PIPE_BARRIER();

        // ---- P1: z row frags 2..3
#pragma unroll
        for (int fi = 0; fi < 2; fi++) {
            int zr = wrow + (fi + 2) * 16 + lm;
            zhf[fi] = *(const bf16x8*)(zhB + zr * 64 + cbx);
            zlf[fi] = *(const bf16x8*)(zlB + zr * 64 + cbx);
        }
        PIPE_BARRIER();
        asm volatile("s_waitcnt lgkmcnt(0)" ::: "memory");
        __builtin_amdgcn_sched_barrier(0);
        __builtin_amdgcn_s_setprio(1);
#pragma unroll
        for (int fi = 0; fi < 2; fi++)
#pragma unroll
            for (int fj = 0; fj < 4; fj++) {
                MFMA3(acc[fi + 2][fj], zhf[fi], zlf[fi], ahf[fj], alf[fj]);
            }
        __builtin_amdgcn_s_setprio(0);
        asm volatile("s_waitcnt vmcnt(0)" ::: "memory");
        PIPE_BARRIER();
    }

    // ---- combine groups via LDS (padded stride 132 f32), then epilogue ----
    float* cmb = (float*)smem;                     // 128 x 132 f32 = 67.5KB
    __syncthreads();
    if (g == 1) {
#pragma unroll
        for (int fi = 0; fi < 4; fi++)
#pragma unroll
            for (int fj = 0; fj < 4; fj++)
#pragma unroll
                for (int r = 0; r < 4; r++) {
                    int row = wrow + fi * 16 + quad * 4 + r;
                    int col = wcol + fj * 16 + lm;
                    cmb[row * 132 + col] = acc[fi][fj][r];
                }
    }
    __syncthreads();
    if (g == 0) {
#pragma unroll
        for (int fi = 0; fi < 4; fi++)
#pragma unroll
            for (int fj = 0; fj < 4; fj++)
#pragma unroll
                for (int r = 0; r < 4; r++) {
                    int row = wrow + fi * 16 + quad * 4 + r;
                    int col = wcol + fj * 16 + lm;
                    float bv = acc[fi][fj][r] + cmb[row * 132 + col]
                             - y[(size_t)(r0 + row) * Mdim + (m0 + col)];
                    unsigned short h = f2bf(bv);
                    bS[(size_t)(r0 + row) * 1024 + (m0 + col)]       = h;
                    bS[(size_t)(r0 + row) * 1024 + 512 + (m0 + col)] = f2bf(bv - bf2f(h));
                }
    }
}

// ---------------------------------------------------------------------------
// GEMM2 (NN): c[r][n] = sum_m b[r][m]*A[m][n], c fp32.   (r4 winner, unchanged)
// ---------------------------------------------------------------------------
__global__ __launch_bounds__(512, 2) void gemm2_mfma(
    const unsigned short* __restrict__ bS,
    const unsigned short* __restrict__ AhT, const unsigned short* __restrict__ AlT,
    float* __restrict__ c)
{
    enum { NT = 16 };                              // K = 512 / BK=32
    const int tid  = threadIdx.x;
    const int lane = tid & 63, w = tid >> 6;       // 8 waves
    const int lm   = lane & 15, quad = lane >> 4;
    const int wrow = (w >> 2) * 128;               // 2 row-waves
    const int wcol = (w & 3) * 64;                 // 4 col-waves

    // bijective XCD swizzle (nwg=256, %8==0)
    int d   = blockIdx.y * gridDim.x + blockIdx.x;
    int sid = (d & 7) * 32 + (d >> 3);
    const int n0 = (sid & 7) * 256, r0 = (sid >> 3) * 256;

    __shared__ __attribute__((aligned(16))) unsigned short smem[2 * 32768];

    f32x4 acc[8][4];
#pragma unroll
    for (int i = 0; i < 8; i++)
#pragma unroll
        for (int j = 0; j < 4; j++) acc[i][j] = (f32x4)0.f;

    const unsigned short *bhp[2], *blp[2], *ahp[2], *alp[2]; int doff[2];
#pragma unroll
    for (int s = 0; s < 2; s++) {
        int off = ((w * 2 + s) << 10) + lane * 16;            // byte in plane
        int row = off >> 6;                                   // 0..255
        int kb  = (off & 63) ^ (((row >> 1) & 3) << 4);       // swizzled slot
        doff[s] = (w * 2 + s) << 10;
        bhp[s]  = bS  + (size_t)(r0 + row) * 1024 + (kb >> 1);
        blp[s]  = bS  + (size_t)(r0 + row) * 1024 + 512 + (kb >> 1);
        ahp[s]  = AhT + (size_t)(n0 + row) * 512 + (kb >> 1);
        alp[s]  = AlT + (size_t)(n0 + row) * 512 + (kb >> 1);
    }

    const int X   = ((lm >> 1) & 3) << 4;
    const int cbx = (quad * 16) ^ X;

    auto STAGE = [&](int t) {
        char* base = (char*)smem + (t & 1) * 65536;
        const int ko = t * 32;
#pragma unroll
        for (int s = 0; s < 2; s++) {
            gl16(bhp[s] + ko, base +     0 + doff[s]);
            gl16(blp[s] + ko, base + 16384 + doff[s]);
            gl16(ahp[s] + ko, base + 32768 + doff[s]);
            gl16(alp[s] + ko, base + 49152 + doff[s]);
        }
    };

    STAGE(0);
    asm volatile("s_waitcnt vmcnt(0)" ::: "memory");
    PIPE_BARRIER();

#pragma unroll 2
    for (int t = 0; t < NT; ++t) {
        const char* B0  = (const char*)smem + (t & 1) * 65536;
        const char* bhB = B0, *blB = B0 + 16384;
        const char* ahB = B0 + 32768, *alB = B0 + 49152;

        bf16x8 ahf[4], alf[4], bhf[4], blf[4];
#pragma unroll
        for (int fj = 0; fj < 4; fj++) {
            int ar = wcol + fj * 16 + lm;
            ahf[fj] = *(const bf16x8*)(ahB + ar * 64 + cbx);
            alf[fj] = *(const bf16x8*)(alB + ar * 64 + cbx);
        }
#pragma unroll
        for (int fi = 0; fi < 4; fi++) {
            int br = wrow + fi * 16 + lm;
            bhf[fi] = *(const bf16x8*)(bhB + br * 64 + cbx);
            blf[fi] = *(const bf16x8*)(blB + br * 64 + cbx);
        }
        if (t + 1 < NT) STAGE(t + 1);
        PIPE_BARRIER();
        asm volatile("s_waitcnt lgkmcnt(0)" ::: "memory");
        __builtin_amdgcn_sched_barrier(0);
        __builtin_amdgcn_s_setprio(1);
#pragma unroll
        for (int fi = 0; fi < 4; fi++)
#pragma unroll
            for (int fj = 0; fj < 4; fj++) {
                MFMA3(acc[fi][fj], bhf[fi], blf[fi], ahf[fj], alf[fj]);
            }
        __builtin_amdgcn_s_setprio(0);
        PIPE_BARRIER();

#pragma unroll
        for (int fi = 0; fi < 4; fi++) {
            int br = wrow + (fi + 4) * 16 + lm;
            bhf[fi] = *(const bf16x8*)(bhB + br * 64 + cbx);
            blf[fi] = *(const bf16x8*)(blB + br * 64 + cbx);
        }
        PIPE_BARRIER();
        asm volatile("s_waitcnt lgkmcnt(0)" ::: "memory");
        __builtin_amdgcn_sched_barrier(0);
        __builtin_amdgcn_s_setprio(1);
#pragma unroll
        for (int fi = 0; fi < 4; fi++)
#pragma unroll
            for (int fj = 0; fj < 4; fj++) {
                MFMA3(acc[fi + 4][fj], bhf[fi], blf[fi], ahf[fj], alf[fj]);
            }
        __builtin_amdgcn_s_setprio(0);
        asm volatile("s_waitcnt vmcnt(0)" ::: "memory");
        PIPE_BARRIER();
    }

#pragma unroll
    for (int fi = 0; fi < 8; fi++)
#pragma unroll
        for (int fj = 0; fj < 4; fj++)
#pragma unroll
            for (int r = 0; r < 4; r++) {
                int row = r0 + wrow + fi * 16 + quad * 4 + r;
                int col = n0 + wcol + fj * 16 + lm;
                c[(size_t)row * Ndim + col] = acc[fi][fj][r];
            }
}

// ---------------------------------------------------------------------------
// Fused per-row: u = x - gamma*c; exact 50th-largest |u| via 3-pass radix
// (11/11/9 bits, 2048-bin histogram -> ~6x less atomic clustering than 8-bit
// passes on the exponent); soft-threshold + overshoot; write x; write z
// planes in place of c.
// ---------------------------------------------------------------------------
__global__ __launch_bounds__(256) void topk_update_kernel(
    float* __restrict__ uz, float* __restrict__ x,
    const float* __restrict__ gamma, const float* __restrict__ theta,
    const float* __restrict__ a_param, const float* __restrict__ vv,
    const float* __restrict__ vu, int it)
{
    const int row = blockIdx.x;
    const int t   = threadIdx.x;
    float* crow = uz + (size_t)row * Ndim;
    float* xrow = x  + (size_t)row * Ndim;
    const float g = gamma[it];

    float4 c0 = *(const float4*)(crow + 4 * t);
    float4 c1 = *(const float4*)(crow + 4 * t + 1024);
    float4 x0 = *(const float4*)(xrow + 4 * t);
    float4 x1 = *(const float4*)(xrow + 4 * t + 1024);
    float cv[8] = { c0.x, c0.y, c0.z, c0.w, c1.x, c1.y, c1.z, c1.w };
    float xv[8] = { x0.x, x0.y, x0.z, x0.w, x1.x, x1.y, x1.z, x1.w };

    float uvals[8];
    unsigned keys[8];
#pragma unroll
    for (int e = 0; e < 8; e++) {
        uvals[e] = xv[e] - g * cv[e];
        keys[e]  = __float_as_uint(fabsf(uvals[e]));
    }

    __shared__ unsigned bins[2048];
    __shared__ unsigned sel[2];
    __shared__ unsigned wsum[4];

    unsigned prefix = 0;
    unsigned k = Pk;
#pragma unroll
    for (int pass = 0; pass < 3; ++pass) {
        const int      shift  = (pass == 0) ? 20 : (pass == 1) ? 9 : 0;
        const unsigned cmask  = (pass == 2) ? 511u : 2047u;
        const unsigned himask = (pass == 0) ? 0u
                              : (pass == 1) ? (0xFFFFFFFFu << 20)
                                            : (0xFFFFFFFFu << 9);
        uint4 zz = { 0u, 0u, 0u, 0u };
        ((uint4*)bins)[t]       = zz;
        ((uint4*)bins)[t + 256] = zz;
        __syncthreads();
#pragma unroll
        for (int e = 0; e < 8; e++) {
            if ((keys[e] & himask) == prefix)
                atomicAdd(&bins[(keys[e] >> shift) & cmask], 1u);
        }
        __syncthreads();
        // hierarchical top-down scan: thread t owns descending ranks [8t,8t+8)
        const int base = 2040 - 8 * t;                 // t=0 -> bins 2040..2047
        uint4 q0 = *(const uint4*)&bins[base];
        uint4 q1 = *(const uint4*)&bins[base + 4];
        unsigned s  = q0.x + q0.y + q0.z + q0.w + q1.x + q1.y + q1.z + q1.w;
        unsigned sc = s;
        const int ln = t & 63;
#pragma unroll
        for (int off = 1; off < 64; off <<= 1) {
            unsigned o = __shfl_up(sc, (unsigned)off);
            if (ln >= off) sc += o;
        }
        if (ln == 63) wsum[t >> 6] = sc;
        __syncthreads();
        unsigned wpre = 0;
#pragma unroll
        for (int ww = 0; ww < 3; ww++)
            if (ww < (t >> 6)) wpre += wsum[ww];
        unsigned pre = wpre + sc - s;                  // exclusive, descending
        if (pre < k && pre + s >= k) {
            unsigned vals[8] = { q1.w, q1.z, q1.y, q1.x, q0.w, q0.z, q0.y, q0.x };
            unsigned p2 = pre;
#pragma unroll
            for (int j = 0; j < 8; j++) {
                unsigned cb = vals[j];
                if (p2 < k && p2 + cb >= k) { sel[0] = (unsigned)(base + 7 - j); sel[1] = k - p2; }
                p2 += cb;
            }
        }
        __syncthreads();
        prefix |= sel[0] << shift;
        k = sel[1];
    }
    const float thresh = __uint_as_float(prefix);

    const float th = theta[it];
    const float ap = a_param[it];
    const bool haveNext = (it + 1) < Kit;
    float tn = 0.f, vn = 0.f, vun = 0.f;
    if (haveNext) { tn = theta[it + 1]; vn = vv[it + 1]; vun = vu[it + 1]; }

    float xo[8];
    unsigned short zh8[8], zl8[8];
#pragma unroll
    for (int e = 0; e < 8; e++) {
        float uval = uvals[e];
        float au   = fabsf(uval);
        bool keep  = au > thresh;
        float shr  = copysignf(fmaxf(au - th, 0.f), uval);
        float xn   = keep ? uval : shr;
        float dlt  = xn - xv[e];
        float ov   = 1.f + ap / (fabsf(dlt) + EPSv);
        float xr   = xv[e] + ov * dlt;
        xo[e] = xr;
        float z = (1.f + tn * vun * __expf(-vn * fabsf(xr))) * xr;
        unsigned short h = f2bf(z);
        zh8[e] = h;
        zl8[e] = f2bf(z - bf2f(h));
    }
    float4 a0 = { xo[0], xo[1], xo[2], xo[3] };
    float4 a1 = { xo[4], xo[5], xo[6], xo[7] };
    *(float4*)(xrow + 4 * t) = a0;
    *(float4*)(xrow + 4 * t + 1024) = a1;
    if (haveNext) {
        unsigned short* zp = (unsigned short*)crow;   // row block: [zh 2048][zl 2048]
        *(ushort4*)(zp + 4 * t)        = make_ushort4(zh8[0], zh8[1], zh8[2], zh8[3]);
        *(ushort4*)(zp + 1024 + 4 * t) = make_ushort4(zh8[4], zh8[5], zh8[6], zh8[7]);
        *(ushort4*)(zp + 2048 + 4 * t) = make_ushort4(zl8[0], zl8[1], zl8[2], zl8[3]);
        *(ushort4*)(zp + 3072 + 4 * t) = make_ushort4(zl8[4], zl8[5], zl8[6], zl8[7]);
    }
}

// ---------------------------------------------------------------------------
extern "C" void kernel_launch(void* const* d_in, const int* in_sizes, int n_in,
                              void* d_out, int out_size, void* d_ws, size_t ws_size,
                              hipStream_t stream) {
    const float* y       = (const float*)d_in[0];   // (B,M)
    const float* A       = (const float*)d_in[1];   // (M,N)
    const float* gamma   = (const float*)d_in[2];
    const float* theta   = (const float*)d_in[3];
    const float* a_param = (const float*)d_in[4];
    const float* v       = (const float*)d_in[5];
    const float* vu      = (const float*)d_in[6];
    // d_in[7] theta_init (unused: multiplies x==0), d_in[8] info (unused)

    float* x = (float*)d_out;                       // (B,N) + 2K zeros

    // workspace layout (88 MB total)
    char* ws = (char*)d_ws;
    float*          uz = (float*)ws;                                  // 64 MB: c fp32 / z planes
    unsigned short* bS = (unsigned short*)(ws + (size_t)Bsz * Ndim * 4); // 16 MB: b planes
    unsigned short* Ah = (unsigned short*)(ws + (size_t)80 * 1024 * 1024);
    unsigned short* Al  = Ah  + (size_t)Mdim * Ndim;                  // 2 MB each
    unsigned short* AhT = Al  + (size_t)Mdim * Ndim;
    unsigned short* AlT = AhT + (size_t)Mdim * Ndim;

    hipMemsetAsync(d_out, 0, (size_t)out_size * sizeof(float), stream);

    dim3 g1(Mdim / 128, Bsz / 128);     // 4 x 64 = 256 blocks (1/CU)
    dim3 g2(Ndim / 256, Bsz / 256);     // 8 x 32 = 256 blocks

    presplit_A<<<(Mdim * Ndim) / 256, dim3(256), 0, stream>>>(A, Ah, Al, AhT, AlT);
    split_negy_kernel<<<(Bsz * Mdim / 4) / 256, dim3(256), 0, stream>>>(y, bS);

    for (int it = 0; it < Kit; ++it) {
        if (it > 0)
            gemm1_mfma<<<g1, dim3(512), 0, stream>>>((const unsigned short*)uz, Ah, Al, y, bS);
        gemm2_mfma<<<g2, dim3(512), 0, stream>>>(bS, AhT, AlT, uz);
        topk_update_kernel<<<Bsz, dim3(256), 0, stream>>>(uz, x, gamma, theta, a_param, v, vu, it);
    }
}

// Round 7
// 2300.139 us; speedup vs baseline: 1.2802x; 1.0537x over previous
//
#include <hip/hip_runtime.h>
#include <math.h>

#define Bsz  8192
#define Mdim 512
#define Ndim 2048
#define Kit  16
#define Pk   50
#define EPSv 0.01f

typedef __attribute__((ext_vector_type(8))) short bf16x8;
typedef __attribute__((ext_vector_type(4))) float f32x4;

// ---- bf16 split helpers: x = h + l ----------------------------------------
static __device__ __forceinline__ unsigned short f2bf(float f) {
    unsigned u = __float_as_uint(f);
    return (unsigned short)((u + 0x7fffu + ((u >> 16) & 1u)) >> 16);  // RNE
}
static __device__ __forceinline__ float bf2f(unsigned short h) {
    return __uint_as_float(((unsigned)h) << 16);
}

// ---- async global->LDS, 16B per lane (LDS dest = wave-uniform base) -------
static __device__ __forceinline__ void gl16(const void* g, void* l) {
    __builtin_amdgcn_global_load_lds(
        (const __attribute__((address_space(1))) unsigned int*)g,
        (__attribute__((address_space(3))) unsigned int*)l, 16, 0, 0);
}

#define PIPE_BARRIER() __builtin_amdgcn_s_barrier()

#define MFMA3(acc_, bh_, bl_, ah_, al_)                                           \
    do {                                                                          \
        acc_ = __builtin_amdgcn_mfma_f32_16x16x32_bf16(bh_, ah_, acc_, 0, 0, 0);  \
        acc_ = __builtin_amdgcn_mfma_f32_16x16x32_bf16(bh_, al_, acc_, 0, 0, 0);  \
        acc_ = __builtin_amdgcn_mfma_f32_16x16x32_bf16(bl_, ah_, acc_, 0, 0, 0);  \
    } while (0)

// ---------------------------------------------------------------------------
// One-time: split A into bf16 planes Ah/Al [m][n] and AhT/AlT [n][m].
// ---------------------------------------------------------------------------
__global__ __launch_bounds__(256) void presplit_A(
    const float* __restrict__ A, unsigned short* __restrict__ Ah,
    unsigned short* __restrict__ Al, unsigned short* __restrict__ AhT,
    unsigned short* __restrict__ AlT)
{
    int idx = blockIdx.x * 256 + threadIdx.x;      // 0 .. M*N-1
    int m = idx >> 11, n = idx & (Ndim - 1);
    float a = A[idx];
    unsigned short h = f2bf(a);
    unsigned short l = f2bf(a - bf2f(h));
    Ah[idx] = h; Al[idx] = l;
    AhT[(size_t)n * Mdim + m] = h;
    AlT[(size_t)n * Mdim + m] = l;
}

// ---------------------------------------------------------------------------
// it=0: b = -y, stored as h/l planes. b row layout: [h 512][l 512] shorts.
// ---------------------------------------------------------------------------
__global__ __launch_bounds__(256) void split_negy_kernel(const float* __restrict__ y,
                                                         unsigned short* __restrict__ bS) {
    int i = blockIdx.x * 256 + threadIdx.x;        // float4 index
    float4 v = ((const float4*)y)[i];
    int idx = i * 4;
    int r = idx >> 9, c = idx & 511;
    float f0 = -v.x, f1 = -v.y, f2 = -v.z, f3 = -v.w;
    unsigned short h0 = f2bf(f0), h1 = f2bf(f1), h2 = f2bf(f2), h3 = f2bf(f3);
    ushort4 hv = make_ushort4(h0, h1, h2, h3);
    ushort4 lv = make_ushort4(f2bf(f0 - bf2f(h0)), f2bf(f1 - bf2f(h1)),
                              f2bf(f2 - bf2f(h2)), f2bf(f3 - bf2f(h3)));
    *(ushort4*)(bS + (size_t)r * 1024 + c)       = hv;
    *(ushort4*)(bS + (size_t)r * 1024 + 512 + c) = lv;
}

// ---------------------------------------------------------------------------
// GEMM1 (NT): b[r][m] = sum_n z[r][n]*A[m][n] - y[r][m].
// K-split: 512 thr = 2 K-groups x 4 waves, tile 128x128, per-group K=1024,
// BK=32, NT=32 steps. Register-pipelined: each phase's MFMA consumes frags
// read the PREVIOUS phase; this phase's reads drain under the MFMA.
// A-frags double-set (aE/aO) so A reads are off the critical path too.
// One vmcnt(0)+barrier per K-step. Swizzle: slot ^= ((row>>1)&3)<<4 both sides.
// ---------------------------------------------------------------------------
__global__ __launch_bounds__(512, 2) void gemm1_mfma(
    const unsigned short* __restrict__ zS,
    const unsigned short* __restrict__ Ah, const unsigned short* __restrict__ Al,
    const float* __restrict__ y, unsigned short* __restrict__ bS)
{
    enum { NT = 32 };                              // per-group K-steps: 1024/32
    const int tid  = threadIdx.x;
    const int lane = tid & 63, w = tid >> 6;       // 8 waves
    const int lm   = lane & 15, quad = lane >> 4;
    const int g    = w >> 2;                       // K-group 0/1
    const int wg   = w & 3;
    const int wrow = (wg >> 1) * 64;               // 2r x 2c within group
    const int wcol = (wg & 1) * 64;

    // bijective XCD swizzle (nwg=256, %8==0)
    int d   = blockIdx.y * gridDim.x + blockIdx.x;
    int sid = (d & 7) * 32 + (d >> 3);
    const int m0 = (sid & 3) * 128, r0 = (sid >> 2) * 128;

    // 2 bufs x 64KB = 128KB; per buf: [g][plane zh|zl|ah|al][8KB]
    __shared__ __attribute__((aligned(16))) unsigned short smem[2 * 32768];

    f32x4 acc[4][4];
#pragma unroll
    for (int i = 0; i < 4; i++)
#pragma unroll
        for (int j = 0; j < 4; j++) acc[i][j] = (f32x4)0.f;

    // staging: each 8KB plane = 8 chunks of 1KB; 2 chunks/wave/plane.
    const unsigned short *zhp[2], *zlp[2], *ahp[2], *alp[2]; int doff[2];
#pragma unroll
    for (int s = 0; s < 2; s++) {
        int off = ((wg * 2 + s) << 10) + lane * 16;           // byte in plane
        int row = off >> 6;                                   // 0..127
        int kb  = (off & 63) ^ (((row >> 1) & 3) << 4);       // swizzled slot
        doff[s] = (wg * 2 + s) << 10;
        int kbase = g * 1024 + (kb >> 1);                     // shorts
        zhp[s]  = zS + (size_t)(r0 + row) * 4096 + kbase;
        zlp[s]  = zS + (size_t)(r0 + row) * 4096 + 2048 + kbase;
        ahp[s]  = Ah + (size_t)(m0 + row) * 2048 + kbase;     // row = m index
        alp[s]  = Al + (size_t)(m0 + row) * 2048 + kbase;
    }

    const int X   = ((lm >> 1) & 3) << 4;
    const int cbx = (quad * 16) ^ X;

    auto STAGE = [&](int t) {
        char* base = (char*)smem + (t & 1) * 65536 + g * 32768;
        const int ko = t * 32;
#pragma unroll
        for (int s = 0; s < 2; s++) {
            gl16(zhp[s] + ko, base +     0 + doff[s]);
            gl16(zlp[s] + ko, base +  8192 + doff[s]);
            gl16(ahp[s] + ko, base + 16384 + doff[s]);
            gl16(alp[s] + ko, base + 24576 + doff[s]);
        }
    };

    auto BUF = [&](int t) -> const char* {
        return (const char*)smem + (t & 1) * 65536 + g * 32768;
    };
    auto LD_A = [&](const char* B0, bf16x8 (&ah)[4], bf16x8 (&al)[4]) {
        const char* ahB = B0 + 16384; const char* alB = B0 + 24576;
#pragma unroll
        for (int fj = 0; fj < 4; fj++) {
            int ar = wcol + fj * 16 + lm;
            ah[fj] = *(const bf16x8*)(ahB + ar * 64 + cbx);
            al[fj] = *(const bf16x8*)(alB + ar * 64 + cbx);
        }
    };
    auto LD_Z = [&](const char* B0, int rbase, bf16x8 (&zh)[2], bf16x8 (&zl)[2]) {
        const char* zhB = B0; const char* zlB = B0 + 8192;
#pragma unroll
        for (int fi = 0; fi < 2; fi++) {
            int zr = wrow + (rbase + fi) * 16 + lm;
            zh[fi] = *(const bf16x8*)(zhB + zr * 64 + cbx);
            zl[fi] = *(const bf16x8*)(zlB + zr * 64 + cbx);
        }
    };

    bf16x8 ahE[4], alE[4], ahO[4], alO[4];
    bf16x8 z01h[2], z01l[2], z23h[2], z23l[2];

    // prologue: tile 0 staged, first frags loaded
    STAGE(0);
    asm volatile("s_waitcnt vmcnt(0)" ::: "memory");
    PIPE_BARRIER();
    LD_Z(BUF(0), 0, z01h, z01l);
    LD_A(BUF(0), ahE, alE);

    for (int t = 0; t < NT; t += 2) {
        // ================= step t (A-set E) =================
        // phase A: stage t+1; read z23(t); MFMA rows01 (z01+aE, prefetched)
        STAGE(t + 1);
        LD_Z(BUF(t), 2, z23h, z23l);
        __builtin_amdgcn_sched_barrier(0);
        __builtin_amdgcn_s_setprio(1);
#pragma unroll
        for (int fi = 0; fi < 2; fi++) {
#pragma unroll
            for (int fj = 0; fj < 4; fj++) {
                MFMA3(acc[fi][fj], z01h[fi], z01l[fi], ahE[fj], alE[fj]);
            }
        }
        __builtin_amdgcn_s_setprio(0);
        __builtin_amdgcn_sched_barrier(0);
        // phase B: buf t+1 ready; read z01(t+1)+aO(t+1); MFMA rows23 (z23+aE)
        asm volatile("s_waitcnt vmcnt(0)" ::: "memory");
        PIPE_BARRIER();
        LD_Z(BUF(t + 1), 0, z01h, z01l);
        LD_A(BUF(t + 1), ahO, alO);
        __builtin_amdgcn_sched_barrier(0);
        __builtin_amdgcn_s_setprio(1);
#pragma unroll
        for (int fi = 0; fi < 2; fi++) {
#pragma unroll
            for (int fj = 0; fj < 4; fj++) {
                MFMA3(acc[fi + 2][fj], z23h[fi], z23l[fi], ahE[fj], alE[fj]);
            }
        }
        __builtin_amdgcn_s_setprio(0);
        __builtin_amdgcn_sched_barrier(0);

        // ================= step t+1 (A-set O) =================
        if (t + 2 < NT) STAGE(t + 2);
        LD_Z(BUF(t + 1), 2, z23h, z23l);
        __builtin_amdgcn_sched_barrier(0);
        __builtin_amdgcn_s_setprio(1);
#pragma unroll
        for (int fi = 0; fi < 2; fi++) {
#pragma unroll
            for (int fj = 0; fj < 4; fj++) {
                MFMA3(acc[fi][fj], z01h[fi], z01l[fi], ahO[fj], alO[fj]);
            }
        }
        __builtin_amdgcn_s_setprio(0);
        __builtin_amdgcn_sched_barrier(0);
        asm volatile("s_waitcnt vmcnt(0)" ::: "memory");
        PIPE_BARRIER();
        if (t + 2 < NT) {
            LD_Z(BUF(t + 2), 0, z01h, z01l);
            LD_A(BUF(t + 2), ahE, alE);
        }
        __builtin_amdgcn_sched_barrier(0);
        __builtin_amdgcn_s_setprio(1);
#pragma unroll
        for (int fi = 0; fi < 2; fi++) {
#pragma unroll
            for (int fj = 0; fj < 4; fj++) {
                MFMA3(acc[fi + 2][fj], z23h[fi], z23l[fi], ahO[fj], alO[fj]);
            }
        }
        __builtin_amdgcn_s_setprio(0);
        __builtin_amdgcn_sched_barrier(0);
    }

    // ---- combine groups via LDS (padded stride 132 f32), then epilogue ----
    float* cmb = (float*)smem;                     // 128 x 132 f32 = 67.5KB
    __syncthreads();
    if (g == 1) {
#pragma unroll
        for (int fi = 0; fi < 4; fi++)
#pragma unroll
            for (int fj = 0; fj < 4; fj++)
#pragma unroll
                for (int r = 0; r < 4; r++) {
                    int row = wrow + fi * 16 + quad * 4 + r;
                    int col = wcol + fj * 16 + lm;
                    cmb[row * 132 + col] = acc[fi][fj][r];
                }
    }
    __syncthreads();
    if (g == 0) {
#pragma unroll
        for (int fi = 0; fi < 4; fi++)
#pragma unroll
            for (int fj = 0; fj < 4; fj++)
#pragma unroll
                for (int r = 0; r < 4; r++) {
                    int row = wrow + fi * 16 + quad * 4 + r;
                    int col = wcol + fj * 16 + lm;
                    float bv = acc[fi][fj][r] + cmb[row * 132 + col]
                             - y[(size_t)(r0 + row) * Mdim + (m0 + col)];
                    unsigned short h = f2bf(bv);
                    bS[(size_t)(r0 + row) * 1024 + (m0 + col)]       = h;
                    bS[(size_t)(r0 + row) * 1024 + 512 + (m0 + col)] = f2bf(bv - bf2f(h));
                }
    }
}

// ---------------------------------------------------------------------------
// GEMM2 (NN): c[r][n] = sum_m b[r][m]*A[m][n], c fp32.
// Tile 256x256, 8 waves (2Mx4N, wave 128x64), BK=32, NT=16, dbuf 128KB.
// Register-pipelined like gemm1: MFMA rows0-3 uses b03 read last phase;
// b47 + a read under it; rows4-7 MFMA covers next step's b03 reads.
// ---------------------------------------------------------------------------
__global__ __launch_bounds__(512, 2) void gemm2_mfma(
    const unsigned short* __restrict__ bS,
    const unsigned short* __restrict__ AhT, const unsigned short* __restrict__ AlT,
    float* __restrict__ c)
{
    enum { NT = 16 };                              // K = 512 / BK=32
    const int tid  = threadIdx.x;
    const int lane = tid & 63, w = tid >> 6;       // 8 waves
    const int lm   = lane & 15, quad = lane >> 4;
    const int wrow = (w >> 2) * 128;               // 2 row-waves
    const int wcol = (w & 3) * 64;                 // 4 col-waves

    // bijective XCD swizzle (nwg=256, %8==0)
    int d   = blockIdx.y * gridDim.x + blockIdx.x;
    int sid = (d & 7) * 32 + (d >> 3);
    const int n0 = (sid & 7) * 256, r0 = (sid >> 3) * 256;

    __shared__ __attribute__((aligned(16))) unsigned short smem[2 * 32768];

    f32x4 acc[8][4];
#pragma unroll
    for (int i = 0; i < 8; i++)
#pragma unroll
        for (int j = 0; j < 4; j++) acc[i][j] = (f32x4)0.f;

    const unsigned short *bhp[2], *blp[2], *ahp[2], *alp[2]; int doff[2];
#pragma unroll
    for (int s = 0; s < 2; s++) {
        int off = ((w * 2 + s) << 10) + lane * 16;            // byte in plane
        int row = off >> 6;                                   // 0..255
        int kb  = (off & 63) ^ (((row >> 1) & 3) << 4);       // swizzled slot
        doff[s] = (w * 2 + s) << 10;
        bhp[s]  = bS  + (size_t)(r0 + row) * 1024 + (kb >> 1);
        blp[s]  = bS  + (size_t)(r0 + row) * 1024 + 512 + (kb >> 1);
        ahp[s]  = AhT + (size_t)(n0 + row) * 512 + (kb >> 1);
        alp[s]  = AlT + (size_t)(n0 + row) * 512 + (kb >> 1);
    }

    const int X   = ((lm >> 1) & 3) << 4;
    const int cbx = (quad * 16) ^ X;

    auto STAGE = [&](int t) {
        char* base = (char*)smem + (t & 1) * 65536;
        const int ko = t * 32;
#pragma unroll
        for (int s = 0; s < 2; s++) {
            gl16(bhp[s] + ko, base +     0 + doff[s]);
            gl16(blp[s] + ko, base + 16384 + doff[s]);
            gl16(ahp[s] + ko, base + 32768 + doff[s]);
            gl16(alp[s] + ko, base + 49152 + doff[s]);
        }
    };

    auto BUF = [&](int t) -> const char* {
        return (const char*)smem + (t & 1) * 65536;
    };
    auto LD_A = [&](const char* B0, bf16x8 (&ah)[4], bf16x8 (&al)[4]) {
        const char* ahB = B0 + 32768; const char* alB = B0 + 49152;
#pragma unroll
        for (int fj = 0; fj < 4; fj++) {
            int ar = wcol + fj * 16 + lm;
            ah[fj] = *(const bf16x8*)(ahB + ar * 64 + cbx);
            al[fj] = *(const bf16x8*)(alB + ar * 64 + cbx);
        }
    };
    auto LD_B = [&](const char* B0, int rbase, bf16x8 (&bh)[4], bf16x8 (&bl)[4]) {
        const char* bhB = B0; const char* blB = B0 + 16384;
#pragma unroll
        for (int fi = 0; fi < 4; fi++) {
            int br = wrow + (rbase + fi) * 16 + lm;
            bh[fi] = *(const bf16x8*)(bhB + br * 64 + cbx);
            bl[fi] = *(const bf16x8*)(blB + br * 64 + cbx);
        }
    };

    bf16x8 ahf[4], alf[4], b03h[4], b03l[4], b47h[4], b47l[4];

    STAGE(0);
    asm volatile("s_waitcnt vmcnt(0)" ::: "memory");
    PIPE_BARRIER();
    LD_B(BUF(0), 0, b03h, b03l);

    for (int t = 0; t < NT; ++t) {
        const char* B0 = BUF(t);
        // phase A: stage t+1; read a(t) then b47(t); MFMA rows0-3 (b03+a)
        if (t + 1 < NT) STAGE(t + 1);
        LD_A(B0, ahf, alf);                       // needed by this MFMA (a-first)
        LD_B(B0, 4, b47h, b47l);                  // drains under the MFMA
        __builtin_amdgcn_sched_barrier(0);
        __builtin_amdgcn_s_setprio(1);
#pragma unroll
        for (int fi = 0; fi < 4; fi++) {
#pragma unroll
            for (int fj = 0; fj < 4; fj++) {
                MFMA3(acc[fi][fj], b03h[fi], b03l[fi], ahf[fj], alf[fj]);
            }
        }
        __builtin_amdgcn_s_setprio(0);
        __builtin_amdgcn_sched_barrier(0);
        // phase B: buf t+1 ready; read b03(t+1); MFMA rows4-7 (b47+a)
        asm volatile("s_waitcnt vmcnt(0)" ::: "memory");
        PIPE_BARRIER();
        if (t + 1 < NT) LD_B(BUF(t + 1), 0, b03h, b03l);
        __builtin_amdgcn_sched_barrier(0);
        __builtin_amdgcn_s_setprio(1);
#pragma unroll
        for (int fi = 0; fi < 4; fi++) {
#pragma unroll
            for (int fj = 0; fj < 4; fj++) {
                MFMA3(acc[fi + 4][fj], b47h[fi], b47l[fi], ahf[fj], alf[fj]);
            }
        }
        __builtin_amdgcn_s_setprio(0);
        __builtin_amdgcn_sched_barrier(0);
    }

#pragma unroll
    for (int fi = 0; fi < 8; fi++)
#pragma unroll
        for (int fj = 0; fj < 4; fj++)
#pragma unroll
            for (int r = 0; r < 4; r++) {
                int row = r0 + wrow + fi * 16 + quad * 4 + r;
                int col = n0 + wcol + fj * 16 + lm;
                c[(size_t)row * Ndim + col] = acc[fi][fj][r];
            }
}

// ---------------------------------------------------------------------------
// Fused per-row: u = x - gamma*c; exact 50th-largest |u| via 3-pass radix
// (11/11/9 bits, 2048-bin histogram); soft-threshold + overshoot; write x;
// write z planes in place of c.   (r5 version, unchanged)
// ---------------------------------------------------------------------------
__global__ __launch_bounds__(256) void topk_update_kernel(
    float* __restrict__ uz, float* __restrict__ x,
    const float* __restrict__ gamma, const float* __restrict__ theta,
    const float* __restrict__ a_param, const float* __restrict__ vv,
    const float* __restrict__ vu, int it)
{
    const int row = blockIdx.x;
    const int t   = threadIdx.x;
    float* crow = uz + (size_t)row * Ndim;
    float* xrow = x  + (size_t)row * Ndim;
    const float g = gamma[it];

    float4 c0 = *(const float4*)(crow + 4 * t);
    float4 c1 = *(const float4*)(crow + 4 * t + 1024);
    float4 x0 = *(const float4*)(xrow + 4 * t);
    float4 x1 = *(const float4*)(xrow + 4 * t + 1024);
    float cv[8] = { c0.x, c0.y, c0.z, c0.w, c1.x, c1.y, c1.z, c1.w };
    float xv[8] = { x0.x, x0.y, x0.z, x0.w, x1.x, x1.y, x1.z, x1.w };

    float uvals[8];
    unsigned keys[8];
#pragma unroll
    for (int e = 0; e < 8; e++) {
        uvals[e] = xv[e] - g * cv[e];
        keys[e]  = __float_as_uint(fabsf(uvals[e]));
    }

    __shared__ unsigned bins[2048];
    __shared__ unsigned sel[2];
    __shared__ unsigned wsum[4];

    unsigned prefix = 0;
    unsigned k = Pk;
#pragma unroll
    for (int pass = 0; pass < 3; ++pass) {
        const int      shift  = (pass == 0) ? 20 : (pass == 1) ? 9 : 0;
        const unsigned cmask  = (pass == 2) ? 511u : 2047u;
        const unsigned himask = (pass == 0) ? 0u
                              : (pass == 1) ? (0xFFFFFFFFu << 20)
                                            : (0xFFFFFFFFu << 9);
        uint4 zz = { 0u, 0u, 0u, 0u };
        ((uint4*)bins)[t]       = zz;
        ((uint4*)bins)[t + 256] = zz;
        __syncthreads();
#pragma unroll
        for (int e = 0; e < 8; e++) {
            if ((keys[e] & himask) == prefix)
                atomicAdd(&bins[(keys[e] >> shift) & cmask], 1u);
        }
        __syncthreads();
        // hierarchical top-down scan: thread t owns descending ranks [8t,8t+8)
        const int base = 2040 - 8 * t;                 // t=0 -> bins 2040..2047
        uint4 q0 = *(const uint4*)&bins[base];
        uint4 q1 = *(const uint4*)&bins[base + 4];
        unsigned s  = q0.x + q0.y + q0.z + q0.w + q1.x + q1.y + q1.z + q1.w;
        unsigned sc = s;
        const int ln = t & 63;
#pragma unroll
        for (int off = 1; off < 64; off <<= 1) {
            unsigned o = __shfl_up(sc, (unsigned)off);
            if (ln >= off) sc += o;
        }
        if (ln == 63) wsum[t >> 6] = sc;
        __syncthreads();
        unsigned wpre = 0;
#pragma unroll
        for (int ww = 0; ww < 3; ww++)
            if (ww < (t >> 6)) wpre += wsum[ww];
        unsigned pre = wpre + sc - s;                  // exclusive, descending
        if (pre < k && pre + s >= k) {
            unsigned vals[8] = { q1.w, q1.z, q1.y, q1.x, q0.w, q0.z, q0.y, q0.x };
            unsigned p2 = pre;
#pragma unroll
            for (int j = 0; j < 8; j++) {
                unsigned cb = vals[j];
                if (p2 < k && p2 + cb >= k) { sel[0] = (unsigned)(base + 7 - j); sel[1] = k - p2; }
                p2 += cb;
            }
        }
        __syncthreads();
        prefix |= sel[0] << shift;
        k = sel[1];
    }
    const float thresh = __uint_as_float(prefix);

    const float th = theta[it];
    const float ap = a_param[it];
    const bool haveNext = (it + 1) < Kit;
    float tn = 0.f, vn = 0.f, vun = 0.f;
    if (haveNext) { tn = theta[it + 1]; vn = vv[it + 1]; vun = vu[it + 1]; }

    float xo[8];
    unsigned short zh8[8], zl8[8];
#pragma unroll
    for (int e = 0; e < 8; e++) {
        float uval = uvals[e];
        float au   = fabsf(uval);
        bool keep  = au > thresh;
        float shr  = copysignf(fmaxf(au - th, 0.f), uval);
        float xn   = keep ? uval : shr;
        float dlt  = xn - xv[e];
        float ov   = 1.f + ap / (fabsf(dlt) + EPSv);
        float xr   = xv[e] + ov * dlt;
        xo[e] = xr;
        float z = (1.f + tn * vun * __expf(-vn * fabsf(xr))) * xr;
        unsigned short h = f2bf(z);
        zh8[e] = h;
        zl8[e] = f2bf(z - bf2f(h));
    }
    float4 a0 = { xo[0], xo[1], xo[2], xo[3] };
    float4 a1 = { xo[4], xo[5], xo[6], xo[7] };
    *(float4*)(xrow + 4 * t) = a0;
    *(float4*)(xrow + 4 * t + 1024) = a1;
    if (haveNext) {
        unsigned short* zp = (unsigned short*)crow;   // row block: [zh 2048][zl 2048]
        *(ushort4*)(zp + 4 * t)        = make_ushort4(zh8[0], zh8[1], zh8[2], zh8[3]);
        *(ushort4*)(zp + 1024 + 4 * t) = make_ushort4(zh8[4], zh8[5], zh8[6], zh8[7]);
        *(ushort4*)(zp + 2048 + 4 * t) = make_ushort4(zl8[0], zl8[1], zl8[2], zl8[3]);
        *(ushort4*)(zp + 3072 + 4 * t) = make_ushort4(zl8[4], zl8[5], zl8[6], zl8[7]);
    }
}

// ---------------------------------------------------------------------------
extern "C" void kernel_launch(void* const* d_in, const int* in_sizes, int n_in,
                              void* d_out, int out_size, void* d_ws, size_t ws_size,
                              hipStream_t stream) {
    const float* y       = (const float*)d_in[0];   // (B,M)
    const float* A       = (const float*)d_in[1];   // (M,N)
    const float* gamma   = (const float*)d_in[2];
    const float* theta   = (const float*)d_in[3];
    const float* a_param = (const float*)d_in[4];
    const float* v       = (const float*)d_in[5];
    const float* vu      = (const float*)d_in[6];
    // d_in[7] theta_init (unused: multiplies x==0), d_in[8] info (unused)

    float* x = (float*)d_out;                       // (B,N) + 2K zeros

    // workspace layout (88 MB total)
    char* ws = (char*)d_ws;
    float*          uz = (float*)ws;                                  // 64 MB: c fp32 / z planes
    unsigned short* bS = (unsigned short*)(ws + (size_t)Bsz * Ndim * 4); // 16 MB: b planes
    unsigned short* Ah = (unsigned short*)(ws + (size_t)80 * 1024 * 1024);
    unsigned short* Al  = Ah  + (size_t)Mdim * Ndim;                  // 2 MB each
    unsigned short* AhT = Al  + (size_t)Mdim * Ndim;
    unsigned short* AlT = AhT + (size_t)Mdim * Ndim;

    hipMemsetAsync(d_out, 0, (size_t)out_size * sizeof(float), stream);

    dim3 g1(Mdim / 128, Bsz / 128);     // 4 x 64 = 256 blocks (1/CU)
    dim3 g2(Ndim / 256, Bsz / 256);     // 8 x 32 = 256 blocks

    presplit_A<<<(Mdim * Ndim) / 256, dim3(256), 0, stream>>>(A, Ah, Al, AhT, AlT);
    split_negy_kernel<<<(Bsz * Mdim / 4) / 256, dim3(256), 0, stream>>>(y, bS);

    for (int it = 0; it < Kit; ++it) {
        if (it > 0)
            gemm1_mfma<<<g1, dim3(512), 0, stream>>>((const unsigned short*)uz, Ah, Al, y, bS);
        gemm2_mfma<<<g2, dim3(512), 0, stream>>>(bS, AhT, AlT, uz);
        topk_update_kernel<<<Bsz, dim3(256), 0, stream>>>(uz, x, gamma, theta, a_param, v, vu, it);
    }
}